// Round 1
// 325.114 us; speedup vs baseline: 1.0736x; 1.0736x over previous
//
#include <hip/hip_runtime.h>

// ---------------------------------------------------------------------------
// SegAwareMultiHeadAttention on MI355X (gfx950)
// B=32, N=577, HIDDEN=768, HEADS=12, HEAD_DIM=64
// cast/transpose -> QKV GEMM (bf16 MFMA, BK=64 DMA staging, XCD-remapped) ->
// V-transpose prepass (key-permuted) -> flash attention v3 (dbuf, 1 barrier/
// tile, cvt_pk b64 P-writes, raw v_exp, 3 blocks/CU) -> proj GEMM
// ---------------------------------------------------------------------------

typedef unsigned short bf16_t;
typedef __attribute__((ext_vector_type(8))) short short8;   // 8 bf16 = 16 B
typedef __attribute__((ext_vector_type(4))) short short4v;  // 4 bf16 = 8 B
typedef __attribute__((ext_vector_type(4))) float f32x4;    // MFMA C/D frag

#define B_    32
#define N_    577
#define BN_   18464
#define HID_  768
#define NH_   12
#define HD_   64
#define QKVC_ 2304
#define NPAD_ 640     // keys padded to 10 tiles of 64
#define PB_LD 68      // P LDS stride (elems): 34 dwords == 2 mod 32, 8B-aligned rows

__device__ __forceinline__ bf16_t f2bf(float f) {
  union { float f; unsigned u; } x; x.f = f;
  unsigned r = x.u + 0x7fffu + ((x.u >> 16) & 1u);
  return (bf16_t)(r >> 16);
}

// packed f32x2 -> bf16x2 (RNE); no builtin on gfx950, single VOP3
__device__ __forceinline__ unsigned cvt_pk_bf16(float a, float b) {
  unsigned r;
  asm("v_cvt_pk_bf16_f32 %0, %1, %2" : "=v"(r) : "v"(a), "v"(b));
  return r;
}

// ---------------------------------------------------------------------------
__global__ __launch_bounds__(256) void cast_kernel(const float* __restrict__ in,
                                                   bf16_t* __restrict__ out, int n4) {
  int i = blockIdx.x * 256 + threadIdx.x;
  if (i >= n4) return;
  float4 v = ((const float4*)in)[i];
  ushort4 o;
  o.x = f2bf(v.x); o.y = f2bf(v.y); o.z = f2bf(v.z); o.w = f2bf(v.w);
  ((ushort4*)out)[i] = o;
}

// in fp32 [R][C] -> out bf16 [C][R]
__global__ __launch_bounds__(256) void transpose_cast_kernel(const float* __restrict__ in,
                                                             bf16_t* __restrict__ out,
                                                             int R, int C) {
  __shared__ float tile[32][33];
  int c0 = blockIdx.x * 32, r0 = blockIdx.y * 32;
  int tx = threadIdx.x, ty = threadIdx.y;
  #pragma unroll
  for (int i = ty; i < 32; i += 8)
    tile[i][tx] = in[(size_t)(r0 + i) * C + c0 + tx];
  __syncthreads();
  #pragma unroll
  for (int i = ty; i < 32; i += 8)
    out[(size_t)(c0 + i) * R + r0 + tx] = f2bf(tile[tx][i]);
}

// ---------------------------------------------------------------------------
// GEMM: C[M][Nc] = A[M][768] * Bt[Nc][768]^T + bias. 128x128 tile, BK=64.
// global_load_lds width=16 staging, source-side XOR swizzle, panel remap.
// (unchanged — 0 bank conflicts, panel remap keeps A-strip in L2)
// ---------------------------------------------------------------------------
template <int OUT_BF16>
__global__ __launch_bounds__(256, 3) void gemm_bf16_kernel(
    const bf16_t* __restrict__ A,
    const bf16_t* __restrict__ Bt,
    const float* __restrict__ bias,
    void* __restrict__ Cout,
    int M, int Nc) {
  __shared__ bf16_t As[128 * 64];
  __shared__ bf16_t Bs[128 * 64];

  const int tid  = threadIdx.x;
  const int lane = tid & 63, w = tid >> 6;
  const int quad = lane >> 4, l16 = lane & 15;

  const int Mb = (M + 127) >> 7;
  const int Nb = Nc >> 7;
  const int np_full = Mb >> 3;
  const int rem = Mb - np_full * 8;
  int bid = blockIdx.x;
  int m_blk, n_blk;
  int body = np_full * 8 * Nb;
  if (bid < body) {
    int p = bid / (8 * Nb), local = bid % (8 * Nb);
    m_blk = p * 8 + (local & 7);
    n_blk = local >> 3;
  } else {
    int t = bid - body;
    m_blk = np_full * 8 + t % rem;
    n_blk = t / rem;
  }
  const int m0 = m_blk * 128, n0 = n_blk * 128;
  const int wm = (w >> 1) * 64, wn = (w & 1) * 64;

  f32x4 acc[4][4];
  #pragma unroll
  for (int i = 0; i < 4; ++i)
    #pragma unroll
    for (int j = 0; j < 4; ++j)
      acc[i][j] = (f32x4){0.f, 0.f, 0.f, 0.f};

  for (int kt = 0; kt < 768; kt += 64) {
    __syncthreads();
    #pragma unroll
    for (int it = 0; it < 4; ++it) {
      int gi = it * 256 + tid;
      int row = gi >> 3, chp = gi & 7;
      int ch = chp ^ (row & 7);
      int gm = m0 + row; if (gm >= M) gm = M - 1;
      __builtin_amdgcn_global_load_lds(
          (const __attribute__((address_space(1))) unsigned int*)(A + (size_t)gm * 768 + kt + ch * 8),
          (__attribute__((address_space(3))) unsigned int*)(As + gi * 8),
          16, 0, 0);
      int gn = n0 + row;
      __builtin_amdgcn_global_load_lds(
          (const __attribute__((address_space(1))) unsigned int*)(Bt + (size_t)gn * 768 + kt + ch * 8),
          (__attribute__((address_space(3))) unsigned int*)(Bs + gi * 8),
          16, 0, 0);
    }
    __syncthreads();

    #pragma unroll
    for (int ks = 0; ks < 2; ++ks) {
      short8 af[4], bfr[4];
      #pragma unroll
      for (int i = 0; i < 4; ++i) {
        int row = wm + i * 16 + l16;
        int c = ks * 4 + quad;
        af[i] = *(const short8*)(As + row * 64 + (c ^ (row & 7)) * 8);
      }
      #pragma unroll
      for (int j = 0; j < 4; ++j) {
        int row = wn + j * 16 + l16;
        int c = ks * 4 + quad;
        bfr[j] = *(const short8*)(Bs + row * 64 + (c ^ (row & 7)) * 8);
      }
      #pragma unroll
      for (int i = 0; i < 4; ++i)
        #pragma unroll
        for (int j = 0; j < 4; ++j)
          acc[i][j] = __builtin_amdgcn_mfma_f32_16x16x32_bf16(af[i], bfr[j], acc[i][j], 0, 0, 0);
    }
  }

  #pragma unroll
  for (int i = 0; i < 4; ++i) {
    int mrow_base = m0 + wm + i * 16 + quad * 4;
    #pragma unroll
    for (int j = 0; j < 4; ++j) {
      int col = n0 + wn + j * 16 + l16;
      float bs = bias[col];
      #pragma unroll
      for (int r = 0; r < 4; ++r) {
        int row = mrow_base + r;
        if (row < M) {
          float v = acc[i][j][r] + bs;
          if (OUT_BF16)
            ((bf16_t*)Cout)[(size_t)row * Nc + col] = f2bf(v);
          else
            ((float*)Cout)[(size_t)row * Nc + col] = v;
        }
      }
    }
  }
}

// ---------------------------------------------------------------------------
// V transpose prepass: qkv V-slice [key][d] -> vT[bh][d=64][NPAD_ keys]
// Keys PERMUTED within each 64-tile: physical col p holds actual key
// k(p) = ((p&3)<<4) | (p>>2)  (inverse of phi(k) = (k&15)*4 + (k>>4)).
// P columns in attn use phi(k), so the PV MFMA k-dim stays consistent;
// sum over k is permutation-invariant.
// ---------------------------------------------------------------------------
__global__ __launch_bounds__(256) void vt_kernel(const bf16_t* __restrict__ qkv,
                                                 bf16_t* __restrict__ vT) {
  const int t = blockIdx.x, h = blockIdx.y, b = blockIdx.z;
  const int tid = threadIdx.x;
  __shared__ bf16_t Ls[64 * 65];
  const int kv0 = t * 64;
  const bf16_t* Vp = qkv + (size_t)b * N_ * QKVC_ + 2 * HID_ + h * HD_;

  #pragma unroll
  for (int it = 0; it < 2; ++it) {
    int idx = it * 256 + tid;
    int row = idx >> 3, ch = idx & 7;
    int krow = kv0 + row; if (krow > N_ - 1) krow = N_ - 1;
    short8 v8 = *(const short8*)(Vp + (size_t)krow * QKVC_ + ch * 8);
    #pragma unroll
    for (int j = 0; j < 8; ++j)
      Ls[(ch * 8 + j) * 65 + row] = (bf16_t)v8[j];
  }
  __syncthreads();
  bf16_t* outp = vT + ((size_t)(b * NH_ + h) * HD_) * NPAD_;
  #pragma unroll
  for (int it = 0; it < 2; ++it) {
    int idx = it * 256 + tid;
    int d = idx >> 3, kc = idx & 7;
    short8 o8;
    #pragma unroll
    for (int j = 0; j < 8; ++j) {
      int p = kc * 8 + j;                    // physical col within tile
      int ky = ((p & 3) << 4) | (p >> 2);    // actual key within tile
      o8[j] = (short)Ls[d * 65 + ky];
    }
    *(short8*)(outp + (size_t)d * NPAD_ + kv0 + kc * 8) = o8;
  }
}

// ---------------------------------------------------------------------------
// Flash attention v3. Flat grid 1920: pair = bid%384 (b,h), qt = bid/384 so
// all 5 q-tiles of a pair land on one XCD (384 % 8 == 0) -> K/V L2-resident.
// Double-buffered K/V tiles, ONE barrier per tile (prefetch regs -> LDS).
// VALU diet: scale*log2e folded into Q frags; raw v_exp_f32 (no denorm
// fixup); P packed via v_cvt_pk_bf16_f32 into bank-balanced ds_write_b64
// (key-permuted columns, matching permuted vT); Pb stride 68 -> LDS 54272 B
// -> 3 blocks/CU (was 2).
// ---------------------------------------------------------------------------
__global__ __launch_bounds__(256) void attn_kernel(
    const bf16_t* __restrict__ qkv,       // [BN][2304]
    const bf16_t* __restrict__ vT,        // [bh][64][NPAD_] (key-permuted)
    const float* __restrict__ seg_bias,   // [B][576]
    const float* __restrict__ seg_scale,  // [1]
    bf16_t* __restrict__ out) {           // [BN][768]
  const int bid  = blockIdx.x;
  const int pair = bid % (B_ * NH_);
  const int qt   = bid / (B_ * NH_);     // 0..4
  const int h    = pair % NH_;
  const int b    = pair / NH_;
  const int tid = threadIdx.x;
  const int w = tid >> 6, lane = tid & 63;
  const int quad = lane >> 4, l16 = lane & 15;

  __shared__ bf16_t Ks[2][64 * 72];
  __shared__ bf16_t Vt[2][64 * 72];
  __shared__ bf16_t Pb[4][32 * PB_LD];

  const bf16_t* Qbase = qkv + (size_t)b * N_ * QKVC_ + h * HD_;
  const bf16_t* Kbase = Qbase + HID_;
  const bf16_t* Vtb   = vT + ((size_t)(b * NH_ + h) * HD_) * NPAD_;

  const int q0 = qt * 128 + w * 32;
  short8 qf[2][2];
  #pragma unroll
  for (int mi = 0; mi < 2; ++mi) {
    int qr = q0 + mi * 16 + l16;
    if (qr > N_ - 1) qr = N_ - 1;
    qf[mi][0] = *(const short8*)(Qbase + (size_t)qr * QKVC_ + quad * 8);
    qf[mi][1] = *(const short8*)(Qbase + (size_t)qr * QKVC_ + 32 + quad * 8);
  }
  // fold scale*log2(e) into Q (one extra bf16 rounding on Q, negligible)
  const float qsc = 0.125f * 1.44269504f;
  #pragma unroll
  for (int mi = 0; mi < 2; ++mi)
    #pragma unroll
    for (int c = 0; c < 2; ++c)
      #pragma unroll
      for (int j = 0; j < 8; ++j) {
        unsigned u = ((unsigned)(unsigned short)qf[mi][c][j]) << 16;
        union { unsigned u; float f; } x; x.u = u;
        qf[mi][c][j] = (short)f2bf(x.f * qsc);
      }

  f32x4 o[2][4];
  float lsum[2][4];
  #pragma unroll
  for (int mi = 0; mi < 2; ++mi)
    #pragma unroll
    for (int j = 0; j < 4; ++j) {
      o[mi][j] = (f32x4){0.f, 0.f, 0.f, 0.f};
      lsum[mi][j] = 0.f;
    }

  const float ssl = seg_scale[0] * 1.44269504f;
  const bool bias_wave = (qt == 0 && w == 0);
  bf16_t* pw = Pb[w];

  // staging geometry: 512 granules = 64 rows x 8 chunks, 2 per thread
  const int srow = tid >> 3;          // 0..31 (it adds +32)
  const int sch  = tid & 7;

  // preload tile 0
  short8 kpre[2], vpre[2];
  #pragma unroll
  for (int it = 0; it < 2; ++it) {
    int row = it * 32 + srow;
    int krow = row; if (krow > N_ - 1) krow = N_ - 1;
    kpre[it] = *(const short8*)(Kbase + (size_t)krow * QKVC_ + sch * 8);
    vpre[it] = *(const short8*)(Vtb + (size_t)row * NPAD_ + sch * 8);
  }
  #pragma unroll
  for (int it = 0; it < 2; ++it) {
    int row = it * 32 + srow;
    *(short8*)(&Ks[0][0] + row * 72 + sch * 8) = kpre[it];
    *(short8*)(&Vt[0][0] + row * 72 + sch * 8) = vpre[it];
  }
  __syncthreads();

  for (int t = 0; t < 10; ++t) {
    const int cur = t & 1;
    const int kv0 = t * 64;
    const bf16_t* ks = &Ks[cur][0];
    const bf16_t* vt = &Vt[cur][0];

    // issue prefetch for t+1 (latency hidden behind compute below)
    if (t < 9) {
      const int kv1 = kv0 + 64;
      #pragma unroll
      for (int it = 0; it < 2; ++it) {
        int row = it * 32 + srow;
        int krow = kv1 + row; if (krow > N_ - 1) krow = N_ - 1;
        kpre[it] = *(const short8*)(Kbase + (size_t)krow * QKVC_ + sch * 8);
        vpre[it] = *(const short8*)(Vtb + (size_t)row * NPAD_ + kv1 + sch * 8);
      }
    }

    // S = Q K^T (logits already in log2 domain via Q scaling)
    f32x4 s[2][4];
    #pragma unroll
    for (int mi = 0; mi < 2; ++mi)
      #pragma unroll
      for (int sub = 0; sub < 4; ++sub)
        s[mi][sub] = (f32x4){0.f, 0.f, 0.f, 0.f};
    #pragma unroll
    for (int sub = 0; sub < 4; ++sub) {
      short8 k0 = *(const short8*)(ks + (sub * 16 + l16) * 72 + quad * 8);
      short8 k1 = *(const short8*)(ks + (sub * 16 + l16) * 72 + 32 + quad * 8);
      #pragma unroll
      for (int mi = 0; mi < 2; ++mi) {
        s[mi][sub] = __builtin_amdgcn_mfma_f32_16x16x32_bf16(qf[mi][0], k0, s[mi][sub], 0, 0, 0);
        s[mi][sub] = __builtin_amdgcn_mfma_f32_16x16x32_bf16(qf[mi][1], k1, s[mi][sub], 0, 0, 0);
      }
    }

    // rare CLS-row bias (divergent branch, one wave of one q-block)
    if (bias_wave && quad == 0) {
      #pragma unroll
      for (int sub = 0; sub < 4; ++sub) {
        int key = kv0 + sub * 16 + l16;
        if (key >= 1 && key < N_)
          s[0][sub][0] += seg_bias[b * (N_ - 1) + key - 1] * ssl;
      }
    }

    // softmax: p = exp2(s) via raw v_exp_f32; mask only in (uniform) last
    // tile; pack 4 contiguous (key-permuted) P elems -> one ds_write_b64.
    // S row quad*4+r (within mi block), lane l16 holds actual keys
    // {sub*16+l16} which land at physical cols l16*4+{0..3} = phi(key).
    #pragma unroll
    for (int mi = 0; mi < 2; ++mi)
      #pragma unroll
      for (int r = 0; r < 4; ++r) {
        float p[4];
        #pragma unroll
        for (int sub = 0; sub < 4; ++sub) {
          float v = __builtin_amdgcn_exp2f(s[mi][sub][r]);
          if (t == 9) {
            int key = kv0 + sub * 16 + l16;
            if (key >= N_) v = 0.f;
          }
          lsum[mi][r] += v;
          p[sub] = v;
        }
        uint2 pk;
        pk.x = cvt_pk_bf16(p[0], p[1]);
        pk.y = cvt_pk_bf16(p[2], p[3]);
        *(uint2*)(pw + (mi * 16 + quad * 4 + r) * PB_LD + l16 * 4) = pk;
      }

    // PV (P write->read same-wave: in-order LDS, no barrier needed).
    // A-frag rows are q=l16 (identity map); b64 pairs since 136B rows are
    // only 8B-aligned. Physical key order matches vT staging exactly.
    #pragma unroll
    for (int mi = 0; mi < 2; ++mi) {
      const bf16_t* pr = pw + (mi * 16 + l16) * PB_LD + quad * 8;
      union { short8 v; short4v h[2]; } pa0, pa1;
      pa0.h[0] = *(const short4v*)(pr);
      pa0.h[1] = *(const short4v*)(pr + 4);
      pa1.h[0] = *(const short4v*)(pr + 32);
      pa1.h[1] = *(const short4v*)(pr + 36);
      #pragma unroll
      for (int ds = 0; ds < 4; ++ds) {
        short8 vb0 = *(const short8*)(vt + (ds * 16 + l16) * 72 + quad * 8);
        short8 vb1 = *(const short8*)(vt + (ds * 16 + l16) * 72 + 32 + quad * 8);
        o[mi][ds] = __builtin_amdgcn_mfma_f32_16x16x32_bf16(pa0.v, vb0, o[mi][ds], 0, 0, 0);
        o[mi][ds] = __builtin_amdgcn_mfma_f32_16x16x32_bf16(pa1.v, vb1, o[mi][ds], 0, 0, 0);
      }
    }

    // write prefetch to the other buffer; single barrier covers RAW + WAR
    if (t < 9) {
      bf16_t* ksn = &Ks[1 - cur][0];
      bf16_t* vtn = &Vt[1 - cur][0];
      #pragma unroll
      for (int it = 0; it < 2; ++it) {
        int row = it * 32 + srow;
        *(short8*)(ksn + row * 72 + sch * 8) = kpre[it];
        *(short8*)(vtn + row * 72 + sch * 8) = vpre[it];
      }
    }
    __syncthreads();
  }

  // epilogue: normalize and store (P rounding vs exact lsum: same as prior rounds)
  #pragma unroll
  for (int mi = 0; mi < 2; ++mi)
    #pragma unroll
    for (int r = 0; r < 4; ++r) {
      float l = lsum[mi][r];
      #pragma unroll
      for (int off = 1; off < 16; off <<= 1)
        l += __shfl_xor(l, off);
      float inv = 1.0f / l;
      int row = q0 + mi * 16 + quad * 4 + r;
      if (row < N_) {
        size_t base = ((size_t)b * N_ + row) * HID_ + h * HD_;
        #pragma unroll
        for (int ds = 0; ds < 4; ++ds)
          out[base + ds * 16 + l16] = f2bf(o[mi][ds][r] * inv);
      }
    }
}

// ---------------------------------------------------------------------------
// ws layout (bytes):
//   xb     bf16[BN*768]     @ 0            (28,360,704)  -- reused as attnb
//   wqkvT  bf16[2304*768]   @ 28,360,704   ( 3,538,944)
//   wprojT bf16[768*768]    @ 31,899,648   ( 1,179,648)
//   qkvb   bf16[BN*2304]    @ 33,079,296   (85,082,112)
//   vT     bf16[384*64*640] @ 118,161,408  (31,457,280)
//   total 149,618,688 B
// ---------------------------------------------------------------------------
extern "C" void kernel_launch(void* const* d_in, const int* in_sizes, int n_in,
                              void* d_out, int out_size, void* d_ws, size_t ws_size,
                              hipStream_t stream) {
  const float* x         = (const float*)d_in[0];
  const float* seg_bias  = (const float*)d_in[1];
  const float* w_qkv     = (const float*)d_in[2];
  const float* b_qkv     = (const float*)d_in[3];
  const float* w_proj    = (const float*)d_in[4];
  const float* b_proj    = (const float*)d_in[5];
  const float* seg_scale = (const float*)d_in[6];

  char* ws = (char*)d_ws;
  bf16_t* xb     = (bf16_t*)ws;
  bf16_t* wqkvT  = (bf16_t*)(ws + 28360704);
  bf16_t* wprojT = (bf16_t*)(ws + 31899648);
  bf16_t* qkvb   = (bf16_t*)(ws + 33079296);
  bf16_t* vT     = (bf16_t*)(ws + 118161408);
  bf16_t* attnb  = xb;

  cast_kernel<<<(BN_ * HID_ / 4) / 256, 256, 0, stream>>>(x, xb, BN_ * HID_ / 4);
  dim3 tb(32, 8);
  transpose_cast_kernel<<<dim3(QKVC_ / 32, HID_ / 32), tb, 0, stream>>>(w_qkv, wqkvT, HID_, QKVC_);
  transpose_cast_kernel<<<dim3(HID_ / 32, HID_ / 32), tb, 0, stream>>>(w_proj, wprojT, HID_, HID_);

  gemm_bf16_kernel<1><<<145 * (QKVC_ / 128), 256, 0, stream>>>(
      xb, wqkvT, b_qkv, (void*)qkvb, BN_, QKVC_);

  vt_kernel<<<dim3(10, NH_, B_), 256, 0, stream>>>(qkvb, vT);

  attn_kernel<<<5 * NH_ * B_, 256, 0, stream>>>(qkvb, vT, seg_bias, seg_scale, attnb);

  gemm_bf16_kernel<0><<<145 * (HID_ / 128), 256, 0, stream>>>(
      attnb, wprojT, b_proj, d_out, BN_, HID_);
}

// Round 2
// 324.290 us; speedup vs baseline: 1.0763x; 1.0025x over previous
//
#include <hip/hip_runtime.h>

// ---------------------------------------------------------------------------
// SegAwareMultiHeadAttention on MI355X (gfx950)
// B=32, N=577, HIDDEN=768, HEADS=12, HEAD_DIM=64
// cast/transpose -> QKV GEMM (bf16 MFMA, BK=64 DMA staging, XCD-remapped) ->
// V-transpose prepass (key-permuted) -> flash attention v4:
//   global_load_lds DMA staging (XOR-swizzled source, linear LDS),
//   counted vmcnt(4) + raw barriers (1-tile prefetch stays in flight),
//   lsum via ones-MFMA, peeled tile 9 (1 valid key), no masking in main loop
// -> proj GEMM
// ---------------------------------------------------------------------------

typedef unsigned short bf16_t;
typedef __attribute__((ext_vector_type(8))) short short8;   // 8 bf16 = 16 B
typedef __attribute__((ext_vector_type(4))) short short4v;  // 4 bf16 = 8 B
typedef __attribute__((ext_vector_type(4))) float f32x4;    // MFMA C/D frag

#define B_    32
#define N_    577
#define BN_   18464
#define HID_  768
#define NH_   12
#define HD_   64
#define QKVC_ 2304
#define NPAD_ 640     // keys padded to 10 tiles of 64
#define PB_LD 68      // P LDS stride (elems): 34 dwords == 2 mod 32, 8B-aligned rows

__device__ __forceinline__ bf16_t f2bf(float f) {
  union { float f; unsigned u; } x; x.f = f;
  unsigned r = x.u + 0x7fffu + ((x.u >> 16) & 1u);
  return (bf16_t)(r >> 16);
}

// packed f32x2 -> bf16x2 (RNE); no builtin on gfx950, single VOP3
__device__ __forceinline__ unsigned cvt_pk_bf16(float a, float b) {
  unsigned r;
  asm("v_cvt_pk_bf16_f32 %0, %1, %2" : "=v"(r) : "v"(a), "v"(b));
  return r;
}

// ---------------------------------------------------------------------------
__global__ __launch_bounds__(256) void cast_kernel(const float* __restrict__ in,
                                                   bf16_t* __restrict__ out, int n4) {
  int i = blockIdx.x * 256 + threadIdx.x;
  if (i >= n4) return;
  float4 v = ((const float4*)in)[i];
  ushort4 o;
  o.x = f2bf(v.x); o.y = f2bf(v.y); o.z = f2bf(v.z); o.w = f2bf(v.w);
  ((ushort4*)out)[i] = o;
}

// in fp32 [R][C] -> out bf16 [C][R]
__global__ __launch_bounds__(256) void transpose_cast_kernel(const float* __restrict__ in,
                                                             bf16_t* __restrict__ out,
                                                             int R, int C) {
  __shared__ float tile[32][33];
  int c0 = blockIdx.x * 32, r0 = blockIdx.y * 32;
  int tx = threadIdx.x, ty = threadIdx.y;
  #pragma unroll
  for (int i = ty; i < 32; i += 8)
    tile[i][tx] = in[(size_t)(r0 + i) * C + c0 + tx];
  __syncthreads();
  #pragma unroll
  for (int i = ty; i < 32; i += 8)
    out[(size_t)(c0 + i) * R + r0 + tx] = f2bf(tile[tx][i]);
}

// ---------------------------------------------------------------------------
// GEMM: C[M][Nc] = A[M][768] * Bt[Nc][768]^T + bias. 128x128 tile, BK=64.
// global_load_lds width=16 staging, source-side XOR swizzle, panel remap.
// (unchanged — 0 bank conflicts, panel remap keeps A-strip in L2)
// ---------------------------------------------------------------------------
template <int OUT_BF16>
__global__ __launch_bounds__(256, 3) void gemm_bf16_kernel(
    const bf16_t* __restrict__ A,
    const bf16_t* __restrict__ Bt,
    const float* __restrict__ bias,
    void* __restrict__ Cout,
    int M, int Nc) {
  __shared__ bf16_t As[128 * 64];
  __shared__ bf16_t Bs[128 * 64];

  const int tid  = threadIdx.x;
  const int lane = tid & 63, w = tid >> 6;
  const int quad = lane >> 4, l16 = lane & 15;

  const int Mb = (M + 127) >> 7;
  const int Nb = Nc >> 7;
  const int np_full = Mb >> 3;
  const int rem = Mb - np_full * 8;
  int bid = blockIdx.x;
  int m_blk, n_blk;
  int body = np_full * 8 * Nb;
  if (bid < body) {
    int p = bid / (8 * Nb), local = bid % (8 * Nb);
    m_blk = p * 8 + (local & 7);
    n_blk = local >> 3;
  } else {
    int t = bid - body;
    m_blk = np_full * 8 + t % rem;
    n_blk = t / rem;
  }
  const int m0 = m_blk * 128, n0 = n_blk * 128;
  const int wm = (w >> 1) * 64, wn = (w & 1) * 64;

  f32x4 acc[4][4];
  #pragma unroll
  for (int i = 0; i < 4; ++i)
    #pragma unroll
    for (int j = 0; j < 4; ++j)
      acc[i][j] = (f32x4){0.f, 0.f, 0.f, 0.f};

  for (int kt = 0; kt < 768; kt += 64) {
    __syncthreads();
    #pragma unroll
    for (int it = 0; it < 4; ++it) {
      int gi = it * 256 + tid;
      int row = gi >> 3, chp = gi & 7;
      int ch = chp ^ (row & 7);
      int gm = m0 + row; if (gm >= M) gm = M - 1;
      __builtin_amdgcn_global_load_lds(
          (const __attribute__((address_space(1))) unsigned int*)(A + (size_t)gm * 768 + kt + ch * 8),
          (__attribute__((address_space(3))) unsigned int*)(As + gi * 8),
          16, 0, 0);
      int gn = n0 + row;
      __builtin_amdgcn_global_load_lds(
          (const __attribute__((address_space(1))) unsigned int*)(Bt + (size_t)gn * 768 + kt + ch * 8),
          (__attribute__((address_space(3))) unsigned int*)(Bs + gi * 8),
          16, 0, 0);
    }
    __syncthreads();

    #pragma unroll
    for (int ks = 0; ks < 2; ++ks) {
      short8 af[4], bfr[4];
      #pragma unroll
      for (int i = 0; i < 4; ++i) {
        int row = wm + i * 16 + l16;
        int c = ks * 4 + quad;
        af[i] = *(const short8*)(As + row * 64 + (c ^ (row & 7)) * 8);
      }
      #pragma unroll
      for (int j = 0; j < 4; ++j) {
        int row = wn + j * 16 + l16;
        int c = ks * 4 + quad;
        bfr[j] = *(const short8*)(Bs + row * 64 + (c ^ (row & 7)) * 8);
      }
      #pragma unroll
      for (int i = 0; i < 4; ++i)
        #pragma unroll
        for (int j = 0; j < 4; ++j)
          acc[i][j] = __builtin_amdgcn_mfma_f32_16x16x32_bf16(af[i], bfr[j], acc[i][j], 0, 0, 0);
    }
  }

  #pragma unroll
  for (int i = 0; i < 4; ++i) {
    int mrow_base = m0 + wm + i * 16 + quad * 4;
    #pragma unroll
    for (int j = 0; j < 4; ++j) {
      int col = n0 + wn + j * 16 + l16;
      float bs = bias[col];
      #pragma unroll
      for (int r = 0; r < 4; ++r) {
        int row = mrow_base + r;
        if (row < M) {
          float v = acc[i][j][r] + bs;
          if (OUT_BF16)
            ((bf16_t*)Cout)[(size_t)row * Nc + col] = f2bf(v);
          else
            ((float*)Cout)[(size_t)row * Nc + col] = v;
        }
      }
    }
  }
}

// ---------------------------------------------------------------------------
// V transpose prepass: qkv V-slice [key][d] -> vT[bh][d=64][NPAD_ keys]
// Keys PERMUTED within each 64-tile: physical col p holds actual key
// k(p) = ((p&3)<<4) | (p>>2)  (inverse of phi(k) = (k&15)*4 + (k>>4)).
// P columns in attn use phi(k); sum over k is permutation-invariant.
// Rows >= 577 clamp to key 576 (garbage-free pad; P=0 there).
// ---------------------------------------------------------------------------
__global__ __launch_bounds__(256) void vt_kernel(const bf16_t* __restrict__ qkv,
                                                 bf16_t* __restrict__ vT) {
  const int t = blockIdx.x, h = blockIdx.y, b = blockIdx.z;
  const int tid = threadIdx.x;
  __shared__ bf16_t Ls[64 * 65];
  const int kv0 = t * 64;
  const bf16_t* Vp = qkv + (size_t)b * N_ * QKVC_ + 2 * HID_ + h * HD_;

  #pragma unroll
  for (int it = 0; it < 2; ++it) {
    int idx = it * 256 + tid;
    int row = idx >> 3, ch = idx & 7;
    int krow = kv0 + row; if (krow > N_ - 1) krow = N_ - 1;
    short8 v8 = *(const short8*)(Vp + (size_t)krow * QKVC_ + ch * 8);
    #pragma unroll
    for (int j = 0; j < 8; ++j)
      Ls[(ch * 8 + j) * 65 + row] = (bf16_t)v8[j];
  }
  __syncthreads();
  bf16_t* outp = vT + ((size_t)(b * NH_ + h) * HD_) * NPAD_;
  #pragma unroll
  for (int it = 0; it < 2; ++it) {
    int idx = it * 256 + tid;
    int d = idx >> 3, kc = idx & 7;
    short8 o8;
    #pragma unroll
    for (int j = 0; j < 8; ++j) {
      int p = kc * 8 + j;                    // physical col within tile
      int ky = ((p & 3) << 4) | (p >> 2);    // actual key within tile
      o8[j] = (short)Ls[d * 65 + ky];
    }
    *(short8*)(outp + (size_t)d * NPAD_ + kv0 + kc * 8) = o8;
  }
}

// ---------------------------------------------------------------------------
// Flash attention v4. Flat grid 1920: pair = bid%384 (b,h), qt = bid/384 so
// all 5 q-tiles of a pair land on one XCD (384 % 8 == 0) -> K/V L2-resident.
// K/V staged by global_load_lds (width 16) into linear [64][64] LDS with
// source-side XOR swizzle (ch ^= row&7); fragment reads XOR the column the
// same way -> 0 bank conflicts (same proven pattern as the GEMM above).
// Double buffer with counted s_waitcnt vmcnt(4) + raw s_barrier: the 4
// next-tile DMAs stay in flight across the barrier (no vmcnt(0) drain).
// Row-sum of P via ones-MFMA (replaces 32 VALU adds + epilogue shuffles).
// Main loop t=0..8 has NO masking (keys 0..575 all valid); tile 9 (single
// valid key 576) peeled with 1/4 QK, 1/4 exp, 1/2 PV.
// ---------------------------------------------------------------------------
__global__ __launch_bounds__(256) void attn_kernel(
    const bf16_t* __restrict__ qkv,       // [BN][2304]
    const bf16_t* __restrict__ vT,        // [bh][64][NPAD_] (key-permuted)
    const float* __restrict__ seg_bias,   // [B][576]
    const float* __restrict__ seg_scale,  // [1]
    bf16_t* __restrict__ out) {           // [BN][768]
  const int bid  = blockIdx.x;
  const int pair = bid % (B_ * NH_);
  const int qt   = bid / (B_ * NH_);     // 0..4
  const int h    = pair % NH_;
  const int b    = pair / NH_;
  const int tid = threadIdx.x;
  const int w = tid >> 6, lane = tid & 63;
  const int quad = lane >> 4, l16 = lane & 15;
  const int xsw = l16 & 7;               // frag-read XOR (== row&7 for row=sub*16+l16)

  __shared__ __align__(16) bf16_t Ks[2][64 * 64];
  __shared__ __align__(16) bf16_t Vt[2][64 * 64];
  __shared__ __align__(16) bf16_t Pb[4][32 * PB_LD];

  const bf16_t* Qbase = qkv + (size_t)b * N_ * QKVC_ + h * HD_;
  const bf16_t* Kbase = Qbase + HID_;
  const bf16_t* Vtb   = vT + ((size_t)(b * NH_ + h) * HD_) * NPAD_;

  const float ssl = seg_scale[0] * 1.44269504f;

  // --- prologue: DMA tile 0 into buffer 0 (issued before Q load/scale) ---
  #pragma unroll
  for (int it = 0; it < 2; ++it) {
    int gi = it * 256 + tid;
    int row = gi >> 3;
    int ch = (gi & 7) ^ (row & 7);
    __builtin_amdgcn_global_load_lds(
        (const __attribute__((address_space(1))) unsigned int*)(Kbase + (size_t)row * QKVC_ + ch * 8),
        (__attribute__((address_space(3))) unsigned int*)(&Ks[0][0] + gi * 8), 16, 0, 0);
    __builtin_amdgcn_global_load_lds(
        (const __attribute__((address_space(1))) unsigned int*)(Vtb + (size_t)row * NPAD_ + ch * 8),
        (__attribute__((address_space(3))) unsigned int*)(&Vt[0][0] + gi * 8), 16, 0, 0);
  }

  // --- Q fragments, scale*log2(e) folded in ---
  const int q0 = qt * 128 + w * 32;
  short8 qf[2][2];
  #pragma unroll
  for (int mi = 0; mi < 2; ++mi) {
    int qr = q0 + mi * 16 + l16;
    if (qr > N_ - 1) qr = N_ - 1;
    qf[mi][0] = *(const short8*)(Qbase + (size_t)qr * QKVC_ + quad * 8);
    qf[mi][1] = *(const short8*)(Qbase + (size_t)qr * QKVC_ + 32 + quad * 8);
  }
  const float qsc = 0.125f * 1.44269504f;
  #pragma unroll
  for (int mi = 0; mi < 2; ++mi)
    #pragma unroll
    for (int c = 0; c < 2; ++c)
      #pragma unroll
      for (int j = 0; j < 8; ++j) {
        unsigned u = ((unsigned)(unsigned short)qf[mi][c][j]) << 16;
        union { unsigned u; float f; } x; x.u = u;
        qf[mi][c][j] = (short)f2bf(x.f * qsc);
      }

  const f32x4 z4 = {0.f, 0.f, 0.f, 0.f};
  f32x4 o[2][4];
  f32x4 ls[2];
  #pragma unroll
  for (int mi = 0; mi < 2; ++mi) {
    ls[mi] = z4;
    #pragma unroll
    for (int j = 0; j < 4; ++j) o[mi][j] = z4;
  }

  short8 ones;
  #pragma unroll
  for (int j = 0; j < 8; ++j) ones[j] = (short)0x3F80;   // bf16 1.0

  const bool bias_wave = (qt == 0 && w == 0);
  bf16_t* pw = Pb[w];

  for (int t = 0; t < 9; ++t) {
    const int cur = t & 1;

    // (A) all waves done READING buf[1^cur] -> safe to DMA-overwrite it
    __builtin_amdgcn_s_barrier();
    __builtin_amdgcn_sched_barrier(0);

    // issue 4 DMAs for tile t+1 into buf[1^cur]
    {
      const int kv1 = (t + 1) * 64;
      bf16_t* ksn = &Ks[1 - cur][0];
      bf16_t* vtn = &Vt[1 - cur][0];
      #pragma unroll
      for (int it = 0; it < 2; ++it) {
        int gi = it * 256 + tid;
        int row = gi >> 3;
        int ch = (gi & 7) ^ (row & 7);
        int krow = kv1 + row; if (krow > N_ - 1) krow = N_ - 1;  // binds only at t=8
        __builtin_amdgcn_global_load_lds(
            (const __attribute__((address_space(1))) unsigned int*)(Kbase + (size_t)krow * QKVC_ + ch * 8),
            (__attribute__((address_space(3))) unsigned int*)(ksn + gi * 8), 16, 0, 0);
        __builtin_amdgcn_global_load_lds(
            (const __attribute__((address_space(1))) unsigned int*)(Vtb + (size_t)row * NPAD_ + kv1 + ch * 8),
            (__attribute__((address_space(3))) unsigned int*)(vtn + gi * 8), 16, 0, 0);
      }
    }

    // wait own buf[cur] DMAs (4 newest = tile t+1 stay in flight), then (B)
    asm volatile("s_waitcnt vmcnt(4)" ::: "memory");
    __builtin_amdgcn_sched_barrier(0);
    __builtin_amdgcn_s_barrier();
    __builtin_amdgcn_sched_barrier(0);

    const bf16_t* ks = &Ks[cur][0];
    const bf16_t* vt = &Vt[cur][0];

    // S = Q K^T (log2 domain); C-in = shared zero regs (no per-tile v_movs)
    f32x4 s[2][4];
    __builtin_amdgcn_s_setprio(1);
    #pragma unroll
    for (int sub = 0; sub < 4; ++sub) {
      short8 k0 = *(const short8*)(ks + (sub * 16 + l16) * 64 + (quad ^ xsw) * 8);
      short8 k1 = *(const short8*)(ks + (sub * 16 + l16) * 64 + ((4 + quad) ^ xsw) * 8);
      #pragma unroll
      for (int mi = 0; mi < 2; ++mi) {
        s[mi][sub] = __builtin_amdgcn_mfma_f32_16x16x32_bf16(qf[mi][0], k0, z4, 0, 0, 0);
        s[mi][sub] = __builtin_amdgcn_mfma_f32_16x16x32_bf16(qf[mi][1], k1, s[mi][sub], 0, 0, 0);
      }
    }
    __builtin_amdgcn_s_setprio(0);

    // rare CLS-row bias (keys 1..575 here; key 576 in peeled tile)
    if (bias_wave && quad == 0) {
      const int kv0 = t * 64;
      #pragma unroll
      for (int sub = 0; sub < 4; ++sub) {
        int key = kv0 + sub * 16 + l16;
        if (key >= 1)
          s[0][sub][0] += seg_bias[b * (N_ - 1) + key - 1] * ssl;
      }
    }

    // softmax: p = exp2(s), no masking; pack 4 key-permuted P elems -> b64
    #pragma unroll
    for (int mi = 0; mi < 2; ++mi)
      #pragma unroll
      for (int r = 0; r < 4; ++r) {
        float p0 = __builtin_amdgcn_exp2f(s[mi][0][r]);
        float p1 = __builtin_amdgcn_exp2f(s[mi][1][r]);
        float p2 = __builtin_amdgcn_exp2f(s[mi][2][r]);
        float p3 = __builtin_amdgcn_exp2f(s[mi][3][r]);
        uint2 pk;
        pk.x = cvt_pk_bf16(p0, p1);
        pk.y = cvt_pk_bf16(p2, p3);
        *(uint2*)(pw + (mi * 16 + quad * 4 + r) * PB_LD + l16 * 4) = pk;
      }

    // PV + row-sum via ones-MFMA (P write->read same-wave: in-order LDS)
    #pragma unroll
    for (int mi = 0; mi < 2; ++mi) {
      const bf16_t* pr = pw + (mi * 16 + l16) * PB_LD + quad * 8;
      union { short8 v; short4v hv[2]; } pa0, pa1;
      pa0.hv[0] = *(const short4v*)(pr);
      pa0.hv[1] = *(const short4v*)(pr + 4);
      pa1.hv[0] = *(const short4v*)(pr + 32);
      pa1.hv[1] = *(const short4v*)(pr + 36);
      __builtin_amdgcn_s_setprio(1);
      ls[mi] = __builtin_amdgcn_mfma_f32_16x16x32_bf16(pa0.v, ones, ls[mi], 0, 0, 0);
      ls[mi] = __builtin_amdgcn_mfma_f32_16x16x32_bf16(pa1.v, ones, ls[mi], 0, 0, 0);
      #pragma unroll
      for (int ds = 0; ds < 4; ++ds) {
        short8 vb0 = *(const short8*)(vt + (ds * 16 + l16) * 64 + (quad ^ xsw) * 8);
        short8 vb1 = *(const short8*)(vt + (ds * 16 + l16) * 64 + ((4 + quad) ^ xsw) * 8);
        o[mi][ds] = __builtin_amdgcn_mfma_f32_16x16x32_bf16(pa0.v, vb0, o[mi][ds], 0, 0, 0);
        o[mi][ds] = __builtin_amdgcn_mfma_f32_16x16x32_bf16(pa1.v, vb1, o[mi][ds], 0, 0, 0);
      }
      __builtin_amdgcn_s_setprio(0);
    }
  }

  // --- peeled tile 9: keys 576..639, only key 576 (phys col 0) valid ---
  {
    asm volatile("s_waitcnt vmcnt(0)" ::: "memory");
    __builtin_amdgcn_sched_barrier(0);
    __builtin_amdgcn_s_barrier();
    __builtin_amdgcn_sched_barrier(0);

    const bf16_t* ks = &Ks[1][0];
    const bf16_t* vt = &Vt[1][0];

    // QK: sub = 0 only (keys 576..591; key 576 at l16==0)
    short8 k0 = *(const short8*)(ks + l16 * 64 + (quad ^ xsw) * 8);
    short8 k1 = *(const short8*)(ks + l16 * 64 + ((4 + quad) ^ xsw) * 8);
    f32x4 s9[2];
    #pragma unroll
    for (int mi = 0; mi < 2; ++mi) {
      s9[mi] = __builtin_amdgcn_mfma_f32_16x16x32_bf16(qf[mi][0], k0, z4, 0, 0, 0);
      s9[mi] = __builtin_amdgcn_mfma_f32_16x16x32_bf16(qf[mi][1], k1, s9[mi], 0, 0, 0);
    }
    if (bias_wave && quad == 0 && l16 == 0)
      s9[0][0] += seg_bias[b * (N_ - 1) + (N_ - 2)] * ssl;   // key 576

    #pragma unroll
    for (int mi = 0; mi < 2; ++mi)
      #pragma unroll
      for (int r = 0; r < 4; ++r) {
        float p0 = (l16 == 0) ? __builtin_amdgcn_exp2f(s9[mi][r]) : 0.f;
        uint2 pk;
        pk.x = cvt_pk_bf16(p0, 0.f);
        pk.y = 0u;
        *(uint2*)(pw + (mi * 16 + quad * 4 + r) * PB_LD + l16 * 4) = pk;
      }

    #pragma unroll
    for (int mi = 0; mi < 2; ++mi) {
      const bf16_t* pr = pw + (mi * 16 + l16) * PB_LD + quad * 8;
      union { short8 v; short4v hv[2]; } pa0;
      pa0.hv[0] = *(const short4v*)(pr);
      pa0.hv[1] = *(const short4v*)(pr + 4);
      ls[mi] = __builtin_amdgcn_mfma_f32_16x16x32_bf16(pa0.v, ones, ls[mi], 0, 0, 0);
      #pragma unroll
      for (int ds = 0; ds < 4; ++ds) {
        short8 vb0 = *(const short8*)(vt + (ds * 16 + l16) * 64 + (quad ^ xsw) * 8);
        o[mi][ds] = __builtin_amdgcn_mfma_f32_16x16x32_bf16(pa0.v, vb0, o[mi][ds], 0, 0, 0);
      }
    }
  }

  // epilogue: ls is replicated across l16 (ones-MFMA) -> no shuffle needed
  #pragma unroll
  for (int mi = 0; mi < 2; ++mi)
    #pragma unroll
    for (int r = 0; r < 4; ++r) {
      float inv = 1.0f / ls[mi][r];
      int row = q0 + mi * 16 + quad * 4 + r;
      if (row < N_) {
        size_t base = ((size_t)b * N_ + row) * HID_ + h * HD_;
        #pragma unroll
        for (int ds = 0; ds < 4; ++ds)
          out[base + ds * 16 + l16] = f2bf(o[mi][ds][r] * inv);
      }
    }
}

// ---------------------------------------------------------------------------
// ws layout (bytes):
//   xb     bf16[BN*768]     @ 0            (28,360,704)  -- reused as attnb
//   wqkvT  bf16[2304*768]   @ 28,360,704   ( 3,538,944)
//   wprojT bf16[768*768]    @ 31,899,648   ( 1,179,648)
//   qkvb   bf16[BN*2304]    @ 33,079,296   (85,082,112)
//   vT     bf16[384*64*640] @ 118,161,408  (31,457,280)
//   total 149,618,688 B
// ---------------------------------------------------------------------------
extern "C" void kernel_launch(void* const* d_in, const int* in_sizes, int n_in,
                              void* d_out, int out_size, void* d_ws, size_t ws_size,
                              hipStream_t stream) {
  const float* x         = (const float*)d_in[0];
  const float* seg_bias  = (const float*)d_in[1];
  const float* w_qkv     = (const float*)d_in[2];
  const float* b_qkv     = (const float*)d_in[3];
  const float* w_proj    = (const float*)d_in[4];
  const float* b_proj    = (const float*)d_in[5];
  const float* seg_scale = (const float*)d_in[6];

  char* ws = (char*)d_ws;
  bf16_t* xb     = (bf16_t*)ws;
  bf16_t* wqkvT  = (bf16_t*)(ws + 28360704);
  bf16_t* wprojT = (bf16_t*)(ws + 31899648);
  bf16_t* qkvb   = (bf16_t*)(ws + 33079296);
  bf16_t* vT     = (bf16_t*)(ws + 118161408);
  bf16_t* attnb  = xb;

  cast_kernel<<<(BN_ * HID_ / 4) / 256, 256, 0, stream>>>(x, xb, BN_ * HID_ / 4);
  dim3 tb(32, 8);
  transpose_cast_kernel<<<dim3(QKVC_ / 32, HID_ / 32), tb, 0, stream>>>(w_qkv, wqkvT, HID_, QKVC_);
  transpose_cast_kernel<<<dim3(HID_ / 32, HID_ / 32), tb, 0, stream>>>(w_proj, wprojT, HID_, HID_);

  gemm_bf16_kernel<1><<<145 * (QKVC_ / 128), 256, 0, stream>>>(
      xb, wqkvT, b_qkv, (void*)qkvb, BN_, QKVC_);

  vt_kernel<<<dim3(10, NH_, B_), 256, 0, stream>>>(qkvb, vT);

  attn_kernel<<<5 * NH_ * B_, 256, 0, stream>>>(qkvb, vT, seg_bias, seg_scale, attnb);

  gemm_bf16_kernel<0><<<145 * (HID_ / 128), 256, 0, stream>>>(
      attnb, wprojT, b_proj, d_out, BN_, HID_);
}

// Round 3
// 295.847 us; speedup vs baseline: 1.1798x; 1.0961x over previous
//
#include <hip/hip_runtime.h>

// ---------------------------------------------------------------------------
// SegAwareMultiHeadAttention on MI355X (gfx950)
// B=32, N=577, HIDDEN=768, HEADS=12, HEAD_DIM=64
// cast/transpose -> QKV GEMM (bf16 MFMA, BK=64 DMA staging, XCD-remapped) ->
// V-transpose prepass (key-permuted) -> flash attention v5:
//   512-thread blocks (8 waves), 2 q-tiles per block (tail via MI=1 branch),
//   global_load_lds DMA staging (XOR-swizzled source, linear LDS),
//   counted vmcnt(2) + raw barriers, per-mi 16-row P buffer,
//   lsum via ones-MFMA, peeled tile 9
// -> proj GEMM
// ---------------------------------------------------------------------------

typedef unsigned short bf16_t;
typedef __attribute__((ext_vector_type(8))) short short8;   // 8 bf16 = 16 B
typedef __attribute__((ext_vector_type(4))) short short4v;  // 4 bf16 = 8 B
typedef __attribute__((ext_vector_type(4))) float f32x4;    // MFMA C/D frag

#define B_    32
#define N_    577
#define BN_   18464
#define HID_  768
#define NH_   12
#define HD_   64
#define QKVC_ 2304
#define NPAD_ 640     // keys padded to 10 tiles of 64
#define PB_LD 68      // P LDS stride (elems): 34 dwords == 2 mod 32, 8B-aligned rows

__device__ __forceinline__ bf16_t f2bf(float f) {
  union { float f; unsigned u; } x; x.f = f;
  unsigned r = x.u + 0x7fffu + ((x.u >> 16) & 1u);
  return (bf16_t)(r >> 16);
}

// packed f32x2 -> bf16x2 (RNE); no builtin on gfx950, single VOP3
__device__ __forceinline__ unsigned cvt_pk_bf16(float a, float b) {
  unsigned r;
  asm("v_cvt_pk_bf16_f32 %0, %1, %2" : "=v"(r) : "v"(a), "v"(b));
  return r;
}

// ---------------------------------------------------------------------------
__global__ __launch_bounds__(256) void cast_kernel(const float* __restrict__ in,
                                                   bf16_t* __restrict__ out, int n4) {
  int i = blockIdx.x * 256 + threadIdx.x;
  if (i >= n4) return;
  float4 v = ((const float4*)in)[i];
  ushort4 o;
  o.x = f2bf(v.x); o.y = f2bf(v.y); o.z = f2bf(v.z); o.w = f2bf(v.w);
  ((ushort4*)out)[i] = o;
}

// in fp32 [R][C] -> out bf16 [C][R]
__global__ __launch_bounds__(256) void transpose_cast_kernel(const float* __restrict__ in,
                                                             bf16_t* __restrict__ out,
                                                             int R, int C) {
  __shared__ float tile[32][33];
  int c0 = blockIdx.x * 32, r0 = blockIdx.y * 32;
  int tx = threadIdx.x, ty = threadIdx.y;
  #pragma unroll
  for (int i = ty; i < 32; i += 8)
    tile[i][tx] = in[(size_t)(r0 + i) * C + c0 + tx];
  __syncthreads();
  #pragma unroll
  for (int i = ty; i < 32; i += 8)
    out[(size_t)(c0 + i) * R + r0 + tx] = f2bf(tile[tx][i]);
}

// ---------------------------------------------------------------------------
// GEMM: C[M][Nc] = A[M][768] * Bt[Nc][768]^T + bias. 128x128 tile, BK=64.
// global_load_lds width=16 staging, source-side XOR swizzle, panel remap.
// (unchanged — 0 bank conflicts, panel remap keeps A-strip in L2)
// ---------------------------------------------------------------------------
template <int OUT_BF16>
__global__ __launch_bounds__(256, 3) void gemm_bf16_kernel(
    const bf16_t* __restrict__ A,
    const bf16_t* __restrict__ Bt,
    const float* __restrict__ bias,
    void* __restrict__ Cout,
    int M, int Nc) {
  __shared__ bf16_t As[128 * 64];
  __shared__ bf16_t Bs[128 * 64];

  const int tid  = threadIdx.x;
  const int lane = tid & 63, w = tid >> 6;
  const int quad = lane >> 4, l16 = lane & 15;

  const int Mb = (M + 127) >> 7;
  const int Nb = Nc >> 7;
  const int np_full = Mb >> 3;
  const int rem = Mb - np_full * 8;
  int bid = blockIdx.x;
  int m_blk, n_blk;
  int body = np_full * 8 * Nb;
  if (bid < body) {
    int p = bid / (8 * Nb), local = bid % (8 * Nb);
    m_blk = p * 8 + (local & 7);
    n_blk = local >> 3;
  } else {
    int t = bid - body;
    m_blk = np_full * 8 + t % rem;
    n_blk = t / rem;
  }
  const int m0 = m_blk * 128, n0 = n_blk * 128;
  const int wm = (w >> 1) * 64, wn = (w & 1) * 64;

  f32x4 acc[4][4];
  #pragma unroll
  for (int i = 0; i < 4; ++i)
    #pragma unroll
    for (int j = 0; j < 4; ++j)
      acc[i][j] = (f32x4){0.f, 0.f, 0.f, 0.f};

  for (int kt = 0; kt < 768; kt += 64) {
    __syncthreads();
    #pragma unroll
    for (int it = 0; it < 4; ++it) {
      int gi = it * 256 + tid;
      int row = gi >> 3, chp = gi & 7;
      int ch = chp ^ (row & 7);
      int gm = m0 + row; if (gm >= M) gm = M - 1;
      __builtin_amdgcn_global_load_lds(
          (const __attribute__((address_space(1))) unsigned int*)(A + (size_t)gm * 768 + kt + ch * 8),
          (__attribute__((address_space(3))) unsigned int*)(As + gi * 8),
          16, 0, 0);
      int gn = n0 + row;
      __builtin_amdgcn_global_load_lds(
          (const __attribute__((address_space(1))) unsigned int*)(Bt + (size_t)gn * 768 + kt + ch * 8),
          (__attribute__((address_space(3))) unsigned int*)(Bs + gi * 8),
          16, 0, 0);
    }
    __syncthreads();

    #pragma unroll
    for (int ks = 0; ks < 2; ++ks) {
      short8 af[4], bfr[4];
      #pragma unroll
      for (int i = 0; i < 4; ++i) {
        int row = wm + i * 16 + l16;
        int c = ks * 4 + quad;
        af[i] = *(const short8*)(As + row * 64 + (c ^ (row & 7)) * 8);
      }
      #pragma unroll
      for (int j = 0; j < 4; ++j) {
        int row = wn + j * 16 + l16;
        int c = ks * 4 + quad;
        bfr[j] = *(const short8*)(Bs + row * 64 + (c ^ (row & 7)) * 8);
      }
      #pragma unroll
      for (int i = 0; i < 4; ++i)
        #pragma unroll
        for (int j = 0; j < 4; ++j)
          acc[i][j] = __builtin_amdgcn_mfma_f32_16x16x32_bf16(af[i], bfr[j], acc[i][j], 0, 0, 0);
    }
  }

  #pragma unroll
  for (int i = 0; i < 4; ++i) {
    int mrow_base = m0 + wm + i * 16 + quad * 4;
    #pragma unroll
    for (int j = 0; j < 4; ++j) {
      int col = n0 + wn + j * 16 + l16;
      float bs = bias[col];
      #pragma unroll
      for (int r = 0; r < 4; ++r) {
        int row = mrow_base + r;
        if (row < M) {
          float v = acc[i][j][r] + bs;
          if (OUT_BF16)
            ((bf16_t*)Cout)[(size_t)row * Nc + col] = f2bf(v);
          else
            ((float*)Cout)[(size_t)row * Nc + col] = v;
        }
      }
    }
  }
}

// ---------------------------------------------------------------------------
// V transpose prepass: qkv V-slice [key][d] -> vT[bh][d=64][NPAD_ keys]
// Keys PERMUTED within each 64-tile: physical col p holds actual key
// k(p) = ((p&3)<<4) | (p>>2)  (inverse of phi(k) = (k&15)*4 + (k>>4)).
// P columns in attn use phi(k); sum over k is permutation-invariant.
// Rows >= 577 clamp to key 576 (garbage-free pad; P=0 there).
// ---------------------------------------------------------------------------
__global__ __launch_bounds__(256) void vt_kernel(const bf16_t* __restrict__ qkv,
                                                 bf16_t* __restrict__ vT) {
  const int t = blockIdx.x, h = blockIdx.y, b = blockIdx.z;
  const int tid = threadIdx.x;
  __shared__ bf16_t Ls[64 * 65];
  const int kv0 = t * 64;
  const bf16_t* Vp = qkv + (size_t)b * N_ * QKVC_ + 2 * HID_ + h * HD_;

  #pragma unroll
  for (int it = 0; it < 2; ++it) {
    int idx = it * 256 + tid;
    int row = idx >> 3, ch = idx & 7;
    int krow = kv0 + row; if (krow > N_ - 1) krow = N_ - 1;
    short8 v8 = *(const short8*)(Vp + (size_t)krow * QKVC_ + ch * 8);
    #pragma unroll
    for (int j = 0; j < 8; ++j)
      Ls[(ch * 8 + j) * 65 + row] = (bf16_t)v8[j];
  }
  __syncthreads();
  bf16_t* outp = vT + ((size_t)(b * NH_ + h) * HD_) * NPAD_;
  #pragma unroll
  for (int it = 0; it < 2; ++it) {
    int idx = it * 256 + tid;
    int d = idx >> 3, kc = idx & 7;
    short8 o8;
    #pragma unroll
    for (int j = 0; j < 8; ++j) {
      int p = kc * 8 + j;                    // physical col within tile
      int ky = ((p & 3) << 4) | (p >> 2);    // actual key within tile
      o8[j] = (short)Ls[d * 65 + ky];
    }
    *(short8*)(outp + (size_t)d * NPAD_ + kv0 + kc * 8) = o8;
  }
}

// ---------------------------------------------------------------------------
// Flash attention v5 body. One block = 8 waves (512 thr), MI q-subtiles of
// 16 rows per wave (MI=2: 256 q-rows/block; MI=1: 128-row tail block).
// K/V staged by global_load_lds (width 16, 1 K + 1 V granule per thread per
// tile) into linear [64][64] LDS with source-side XOR swizzle; fragment
// reads XOR the column the same way -> 0 bank conflicts. Double buffer with
// counted s_waitcnt vmcnt(2) + raw s_barrier (next tile's 2 DMAs stay in
// flight). P buffer: per-wave 16 rows, written+read per mi (same-wave
// in-order LDS). Row-sum of P via ones-MFMA. Main loop t=0..8 unmasked;
// tile 9 (single valid key 576) peeled.
// ---------------------------------------------------------------------------
template <int MI>
__device__ __forceinline__ void attn_body(
    int b, int h, int qbase,
    const bf16_t* __restrict__ qkv, const bf16_t* __restrict__ vT,
    const float* __restrict__ seg_bias, const float* __restrict__ seg_scale,
    bf16_t* __restrict__ out,
    bf16_t* Ks0, bf16_t* Ks1, bf16_t* Vt0, bf16_t* Vt1, bf16_t* PbAll) {
  const int tid = threadIdx.x;
  const int w = tid >> 6, lane = tid & 63;
  const int quad = lane >> 4, l16 = lane & 15;
  const int xsw = l16 & 7;               // frag-read XOR (== row&7 for row=sub*16+l16)

  const bf16_t* Qbase = qkv + (size_t)b * N_ * QKVC_ + h * HD_;
  const bf16_t* Kbase = Qbase + HID_;
  const bf16_t* Vtb   = vT + ((size_t)(b * NH_ + h) * HD_) * NPAD_;

  const float ssl = seg_scale[0] * 1.44269504f;

  // --- prologue: DMA tile 0 into buffer 0 (512 granules per array) ---
  {
    int row = tid >> 3;
    int ch = (tid & 7) ^ (row & 7);
    __builtin_amdgcn_global_load_lds(
        (const __attribute__((address_space(1))) unsigned int*)(Kbase + (size_t)row * QKVC_ + ch * 8),
        (__attribute__((address_space(3))) unsigned int*)(Ks0 + tid * 8), 16, 0, 0);
    __builtin_amdgcn_global_load_lds(
        (const __attribute__((address_space(1))) unsigned int*)(Vtb + (size_t)row * NPAD_ + ch * 8),
        (__attribute__((address_space(3))) unsigned int*)(Vt0 + tid * 8), 16, 0, 0);
  }

  // --- Q fragments, scale*log2(e) folded in ---
  const int q0 = qbase + w * (MI * 16);
  short8 qf[MI][2];
  #pragma unroll
  for (int mi = 0; mi < MI; ++mi) {
    int qr = q0 + mi * 16 + l16;
    if (qr > N_ - 1) qr = N_ - 1;
    qf[mi][0] = *(const short8*)(Qbase + (size_t)qr * QKVC_ + quad * 8);
    qf[mi][1] = *(const short8*)(Qbase + (size_t)qr * QKVC_ + 32 + quad * 8);
  }
  const float qsc = 0.125f * 1.44269504f;
  #pragma unroll
  for (int mi = 0; mi < MI; ++mi)
    #pragma unroll
    for (int c = 0; c < 2; ++c)
      #pragma unroll
      for (int j = 0; j < 8; ++j) {
        unsigned u = ((unsigned)(unsigned short)qf[mi][c][j]) << 16;
        union { unsigned u; float f; } x; x.u = u;
        qf[mi][c][j] = (short)f2bf(x.f * qsc);
      }

  const f32x4 z4 = {0.f, 0.f, 0.f, 0.f};
  f32x4 o[MI][4];
  f32x4 ls[MI];
  #pragma unroll
  for (int mi = 0; mi < MI; ++mi) {
    ls[mi] = z4;
    #pragma unroll
    for (int j = 0; j < 4; ++j) o[mi][j] = z4;
  }

  short8 ones;
  #pragma unroll
  for (int j = 0; j < 8; ++j) ones[j] = (short)0x3F80;   // bf16 1.0

  const bool bias_wave = (qbase == 0 && w == 0);
  bf16_t* pw = PbAll + w * 16 * PB_LD;

  for (int t = 0; t < 9; ++t) {
    const int cur = t & 1;

    // (A) all waves done READING buf[1^cur] -> safe to DMA-overwrite it
    __builtin_amdgcn_s_barrier();
    __builtin_amdgcn_sched_barrier(0);

    // issue 2 DMAs for tile t+1 into buf[1^cur]
    {
      const int kv1 = (t + 1) * 64;
      bf16_t* ksn = cur ? Ks0 : Ks1;
      bf16_t* vtn = cur ? Vt0 : Vt1;
      int row = tid >> 3;
      int ch = (tid & 7) ^ (row & 7);
      int krow = kv1 + row; if (krow > N_ - 1) krow = N_ - 1;  // binds only at t=8
      __builtin_amdgcn_global_load_lds(
          (const __attribute__((address_space(1))) unsigned int*)(Kbase + (size_t)krow * QKVC_ + ch * 8),
          (__attribute__((address_space(3))) unsigned int*)(ksn + tid * 8), 16, 0, 0);
      __builtin_amdgcn_global_load_lds(
          (const __attribute__((address_space(1))) unsigned int*)(Vtb + (size_t)row * NPAD_ + kv1 + ch * 8),
          (__attribute__((address_space(3))) unsigned int*)(vtn + tid * 8), 16, 0, 0);
    }

    // wait own buf[cur] DMAs (2 newest = tile t+1 stay in flight), then (B)
    asm volatile("s_waitcnt vmcnt(2)" ::: "memory");
    __builtin_amdgcn_sched_barrier(0);
    __builtin_amdgcn_s_barrier();
    __builtin_amdgcn_sched_barrier(0);

    const bf16_t* ks = cur ? Ks1 : Ks0;
    const bf16_t* vt = cur ? Vt1 : Vt0;

    // S = Q K^T (log2 domain)
    f32x4 s[MI][4];
    __builtin_amdgcn_s_setprio(1);
    #pragma unroll
    for (int sub = 0; sub < 4; ++sub) {
      short8 k0 = *(const short8*)(ks + (sub * 16 + l16) * 64 + (quad ^ xsw) * 8);
      short8 k1 = *(const short8*)(ks + (sub * 16 + l16) * 64 + ((4 + quad) ^ xsw) * 8);
      #pragma unroll
      for (int mi = 0; mi < MI; ++mi) {
        s[mi][sub] = __builtin_amdgcn_mfma_f32_16x16x32_bf16(qf[mi][0], k0, z4, 0, 0, 0);
        s[mi][sub] = __builtin_amdgcn_mfma_f32_16x16x32_bf16(qf[mi][1], k1, s[mi][sub], 0, 0, 0);
      }
    }
    __builtin_amdgcn_s_setprio(0);

    // rare CLS-row bias (keys 1..575 here; key 576 in peeled tile)
    if (bias_wave && quad == 0) {
      const int kv0 = t * 64;
      #pragma unroll
      for (int sub = 0; sub < 4; ++sub) {
        int key = kv0 + sub * 16 + l16;
        if (key >= 1)
          s[0][sub][0] += seg_bias[b * (N_ - 1) + key - 1] * ssl;
      }
    }

    // per-mi: softmax (exp2, pack, b64 write to 16-row P buf) then PV+lsum
    #pragma unroll
    for (int mi = 0; mi < MI; ++mi) {
      #pragma unroll
      for (int r = 0; r < 4; ++r) {
        float p0 = __builtin_amdgcn_exp2f(s[mi][0][r]);
        float p1 = __builtin_amdgcn_exp2f(s[mi][1][r]);
        float p2 = __builtin_amdgcn_exp2f(s[mi][2][r]);
        float p3 = __builtin_amdgcn_exp2f(s[mi][3][r]);
        uint2 pk;
        pk.x = cvt_pk_bf16(p0, p1);
        pk.y = cvt_pk_bf16(p2, p3);
        *(uint2*)(pw + (quad * 4 + r) * PB_LD + l16 * 4) = pk;
      }

      // P write->read same-wave: in-order LDS, no barrier needed
      const bf16_t* pr = pw + l16 * PB_LD + quad * 8;
      union { short8 v; short4v hv[2]; } pa0, pa1;
      pa0.hv[0] = *(const short4v*)(pr);
      pa0.hv[1] = *(const short4v*)(pr + 4);
      pa1.hv[0] = *(const short4v*)(pr + 32);
      pa1.hv[1] = *(const short4v*)(pr + 36);
      __builtin_amdgcn_s_setprio(1);
      ls[mi] = __builtin_amdgcn_mfma_f32_16x16x32_bf16(pa0.v, ones, ls[mi], 0, 0, 0);
      ls[mi] = __builtin_amdgcn_mfma_f32_16x16x32_bf16(pa1.v, ones, ls[mi], 0, 0, 0);
      #pragma unroll
      for (int ds = 0; ds < 4; ++ds) {
        short8 vb0 = *(const short8*)(vt + (ds * 16 + l16) * 64 + (quad ^ xsw) * 8);
        short8 vb1 = *(const short8*)(vt + (ds * 16 + l16) * 64 + ((4 + quad) ^ xsw) * 8);
        o[mi][ds] = __builtin_amdgcn_mfma_f32_16x16x32_bf16(pa0.v, vb0, o[mi][ds], 0, 0, 0);
        o[mi][ds] = __builtin_amdgcn_mfma_f32_16x16x32_bf16(pa1.v, vb1, o[mi][ds], 0, 0, 0);
      }
      __builtin_amdgcn_s_setprio(0);
    }
  }

  // --- peeled tile 9: keys 576..639, only key 576 (phys col 0) valid ---
  {
    asm volatile("s_waitcnt vmcnt(0)" ::: "memory");
    __builtin_amdgcn_sched_barrier(0);
    __builtin_amdgcn_s_barrier();
    __builtin_amdgcn_sched_barrier(0);

    const bf16_t* ks = Ks1;   // tile 9 DMA'd at t=8 (cur=0) into buffer 1
    const bf16_t* vt = Vt1;

    // QK: sub = 0 only (keys 576..591; key 576 at l16==0)
    short8 k0 = *(const short8*)(ks + l16 * 64 + (quad ^ xsw) * 8);
    short8 k1 = *(const short8*)(ks + l16 * 64 + ((4 + quad) ^ xsw) * 8);
    f32x4 s9[MI];
    #pragma unroll
    for (int mi = 0; mi < MI; ++mi) {
      s9[mi] = __builtin_amdgcn_mfma_f32_16x16x32_bf16(qf[mi][0], k0, z4, 0, 0, 0);
      s9[mi] = __builtin_amdgcn_mfma_f32_16x16x32_bf16(qf[mi][1], k1, s9[mi], 0, 0, 0);
    }
    if (bias_wave && quad == 0 && l16 == 0)
      s9[0][0] += seg_bias[b * (N_ - 1) + (N_ - 2)] * ssl;   // key 576

    #pragma unroll
    for (int mi = 0; mi < MI; ++mi) {
      #pragma unroll
      for (int r = 0; r < 4; ++r) {
        float p0 = (l16 == 0) ? __builtin_amdgcn_exp2f(s9[mi][r]) : 0.f;
        uint2 pk;
        pk.x = cvt_pk_bf16(p0, 0.f);
        pk.y = 0u;
        *(uint2*)(pw + (quad * 4 + r) * PB_LD + l16 * 4) = pk;
      }
      const bf16_t* pr = pw + l16 * PB_LD + quad * 8;
      union { short8 v; short4v hv[2]; } pa0;
      pa0.hv[0] = *(const short4v*)(pr);
      pa0.hv[1] = *(const short4v*)(pr + 4);
      ls[mi] = __builtin_amdgcn_mfma_f32_16x16x32_bf16(pa0.v, ones, ls[mi], 0, 0, 0);
      #pragma unroll
      for (int ds = 0; ds < 4; ++ds) {
        short8 vb0 = *(const short8*)(vt + (ds * 16 + l16) * 64 + (quad ^ xsw) * 8);
        o[mi][ds] = __builtin_amdgcn_mfma_f32_16x16x32_bf16(pa0.v, vb0, o[mi][ds], 0, 0, 0);
      }
    }
  }

  // epilogue: ls is replicated across l16 (ones-MFMA) -> no shuffle needed
  #pragma unroll
  for (int mi = 0; mi < MI; ++mi)
    #pragma unroll
    for (int r = 0; r < 4; ++r) {
      float inv = 1.0f / ls[mi][r];
      int row = q0 + mi * 16 + quad * 4 + r;
      if (row < N_) {
        size_t base = ((size_t)b * N_ + row) * HID_ + h * HD_;
        #pragma unroll
        for (int ds = 0; ds < 4; ++ds)
          out[base + ds * 16 + l16] = f2bf(o[mi][ds][r] * inv);
      }
    }
}

// Grid 1152 (512 thr): bid<768 -> MI=2 blocks (q-rows [0,256) or [256,512)),
// bid>=768 -> MI=1 tail (q-rows [512,640)). pair stride 384 == 0 mod 8 and
// 768 == 0 mod 8 keep all blocks of a (b,h) pair on one XCD.
__global__ __launch_bounds__(512) void attn_kernel(
    const bf16_t* __restrict__ qkv,       // [BN][2304]
    const bf16_t* __restrict__ vT,        // [bh][64][NPAD_] (key-permuted)
    const float* __restrict__ seg_bias,   // [B][576]
    const float* __restrict__ seg_scale,  // [1]
    bf16_t* __restrict__ out) {           // [BN][768]
  __shared__ __align__(16) bf16_t Ks[2][64 * 64];
  __shared__ __align__(16) bf16_t Vt[2][64 * 64];
  __shared__ __align__(16) bf16_t Pb[8][16 * PB_LD];

  const int bid = blockIdx.x;
  if (bid < 768) {
    const int pair = bid % 384, qblk = bid / 384;
    attn_body<2>(pair / NH_, pair % NH_, qblk * 256,
                 qkv, vT, seg_bias, seg_scale, out,
                 &Ks[0][0], &Ks[1][0], &Vt[0][0], &Vt[1][0], &Pb[0][0]);
  } else {
    const int pair = bid - 768;
    attn_body<1>(pair / NH_, pair % NH_, 512,
                 qkv, vT, seg_bias, seg_scale, out,
                 &Ks[0][0], &Ks[1][0], &Vt[0][0], &Vt[1][0], &Pb[0][0]);
  }
}

// ---------------------------------------------------------------------------
// ws layout (bytes):
//   xb     bf16[BN*768]     @ 0            (28,360,704)  -- reused as attnb
//   wqkvT  bf16[2304*768]   @ 28,360,704   ( 3,538,944)
//   wprojT bf16[768*768]    @ 31,899,648   ( 1,179,648)
//   qkvb   bf16[BN*2304]    @ 33,079,296   (85,082,112)
//   vT     bf16[384*64*640] @ 118,161,408  (31,457,280)
//   total 149,618,688 B
// ---------------------------------------------------------------------------
extern "C" void kernel_launch(void* const* d_in, const int* in_sizes, int n_in,
                              void* d_out, int out_size, void* d_ws, size_t ws_size,
                              hipStream_t stream) {
  const float* x         = (const float*)d_in[0];
  const float* seg_bias  = (const float*)d_in[1];
  const float* w_qkv     = (const float*)d_in[2];
  const float* b_qkv     = (const float*)d_in[3];
  const float* w_proj    = (const float*)d_in[4];
  const float* b_proj    = (const float*)d_in[5];
  const float* seg_scale = (const float*)d_in[6];

  char* ws = (char*)d_ws;
  bf16_t* xb     = (bf16_t*)ws;
  bf16_t* wqkvT  = (bf16_t*)(ws + 28360704);
  bf16_t* wprojT = (bf16_t*)(ws + 31899648);
  bf16_t* qkvb   = (bf16_t*)(ws + 33079296);
  bf16_t* vT     = (bf16_t*)(ws + 118161408);
  bf16_t* attnb  = xb;

  cast_kernel<<<(BN_ * HID_ / 4) / 256, 256, 0, stream>>>(x, xb, BN_ * HID_ / 4);
  dim3 tb(32, 8);
  transpose_cast_kernel<<<dim3(QKVC_ / 32, HID_ / 32), tb, 0, stream>>>(w_qkv, wqkvT, HID_, QKVC_);
  transpose_cast_kernel<<<dim3(HID_ / 32, HID_ / 32), tb, 0, stream>>>(w_proj, wprojT, HID_, HID_);

  gemm_bf16_kernel<1><<<145 * (QKVC_ / 128), 256, 0, stream>>>(
      xb, wqkvT, b_qkv, (void*)qkvb, BN_, QKVC_);

  vt_kernel<<<dim3(10, NH_, B_), 256, 0, stream>>>(qkvb, vT);

  attn_kernel<<<1152, 512, 0, stream>>>(qkvb, vT, seg_bias, seg_scale, attnb);

  gemm_bf16_kernel<0><<<145 * (HID_ / 128), 256, 0, stream>>>(
      attnb, wprojT, b_proj, d_out, BN_, HID_);
}